// Round 4
// baseline (38.661 us; speedup 1.0000x reference)
//
#include <hip/hip_runtime.h>

namespace {

typedef float f32x4 __attribute__((ext_vector_type(4)));

constexpr int G     = 76;
constexpr int NA    = 3;
constexpr int NC    = 85;              // 5 + 80 channels per anchor
constexpr int GG    = G * G;           // 5776
constexpr int JV    = G / 4;           // 19 float4 per channel row
constexpr int ROWF  = NC * G;          // 6460 floats per tile (one grid-row)
constexpr int ROWV  = ROWF / 4;        // 1615 float4
constexpr int NT    = 256;
constexpr int NIT   = (ROWV + NT - 1) / NT;   // 7 (last partial: tid<79)
constexpr int TPB   = 4;               // tiles per block (76 = 19*4 -> one panel)
constexpr int NPAN  = 16 * NA;         // 48 (b,a) panels
constexpr int NBLK  = NPAN * (G / TPB);// 912 blocks

__device__ __forceinline__ float sigmoidf(float v) {
    return __builtin_amdgcn_rcpf(1.0f + __expf(-v));
}

__global__ __launch_bounds__(NT)
void yolo_decode(const float* __restrict__ x,
                 const float* __restrict__ anchors,
                 const int* __restrict__ img_dim,
                 float* __restrict__ out)
{
    __shared__ alignas(16) float lds[ROWF];

    const int tid  = threadIdx.x;
    const int blk  = blockIdx.x;
    const int pan  = blk / (G / TPB);          // (b,a) panel, 0..47
    const int i0   = (blk % (G / TPB)) * TPB;  // first grid-row of this block
    const int a    = pan % NA;
    const int b    = pan / NA;

    const float stride_f = (float)(*img_dim) / (float)G;   // 8
    const float aw = anchors[2 * a + 0];   // (anchor/stride)*stride cancels
    const float ah = anchors[2 * a + 1];

    const float* __restrict__ xpan =
        x + (size_t)(b * (NA * NC) + a * NC) * GG;
    float* __restrict__ opan =
        out + (size_t)((b * NA + a) * GG) * NC;

    // Tile-invariant per-thread index maps: k4 = it*NT+tid -> (c, j4)
    int cmap[NIT], jmap[NIT];
    bool vmap[NIT];
    #pragma unroll
    for (int it = 0; it < NIT; ++it) {
        const int k4 = it * NT + tid;
        vmap[it] = (k4 < ROWV);
        cmap[it] = k4 / JV;
        jmap[it] = k4 - cmap[it] * JV;
    }

    // Prologue: loads for tile 0
    f32x4 v[NIT];
    #pragma unroll
    for (int it = 0; it < NIT; ++it)
        if (vmap[it])
            v[it] = *reinterpret_cast<const f32x4*>(
                xpan + (size_t)cmap[it] * GG + (size_t)i0 * G + jmap[it] * 4);

    #pragma unroll
    for (int t = 0; t < TPB; ++t) {
        const int i = i0 + t;
        const float fi = (float)i;

        // Transform current tile's registers -> LDS transposed [j][c]
        #pragma unroll
        for (int it = 0; it < NIT; ++it) {
            if (vmap[it]) {
                const int c = cmap[it];
                #pragma unroll
                for (int e = 0; e < 4; ++e) {
                    const int j = jmap[it] * 4 + e;
                    const float val = v[it][e];
                    float rr;
                    if (c == 0)      rr = (sigmoidf(val) + (float)j) * stride_f;
                    else if (c == 1) rr = (sigmoidf(val) + fi) * stride_f;
                    else if (c == 2) rr = __expf(val) * aw;
                    else if (c == 3) rr = __expf(val) * ah;
                    else             rr = sigmoidf(val);
                    lds[j * NC + c] = rr;
                }
            }
        }
        __syncthreads();

        // Issue next tile's global loads NOW; they fly during the store phase.
        f32x4 w[NIT];
        if (t + 1 < TPB) {
            #pragma unroll
            for (int it = 0; it < NIT; ++it)
                if (vmap[it])
                    w[it] = *reinterpret_cast<const f32x4*>(
                        xpan + (size_t)cmap[it] * GG + (size_t)(i + 1) * G + jmap[it] * 4);
        }

        // Store: 25,840 contiguous bytes, nontemporal float4
        const f32x4* __restrict__ l4 = reinterpret_cast<const f32x4*>(lds);
        f32x4* __restrict__ o4p =
            reinterpret_cast<f32x4*>(opan + (size_t)i * G * NC);
        #pragma unroll
        for (int it = 0; it < NIT; ++it) {
            const int o4 = it * NT + tid;
            if (it < NIT - 1 || o4 < ROWV)
                __builtin_nontemporal_store(l4[o4], o4p + o4);
        }
        __syncthreads();   // LDS fully consumed; safe to overwrite next iter

        #pragma unroll
        for (int it = 0; it < NIT; ++it) v[it] = w[it];
    }
}

} // namespace

extern "C" void kernel_launch(void* const* d_in, const int* in_sizes, int n_in,
                              void* d_out, int out_size, void* d_ws, size_t ws_size,
                              hipStream_t stream) {
    const float* x       = (const float*)d_in[0];
    const float* anchors = (const float*)d_in[1];
    const int*   img_dim = (const int*)d_in[2];
    float* outp = (float*)d_out;

    yolo_decode<<<NBLK, NT, 0, stream>>>(x, anchors, img_dim, outp);
}